// Round 7
// baseline (218.381 us; speedup 1.0000x reference)
//
#include <hip/hip_runtime.h>
#include <hip/hip_bf16.h>

// AtomPoolingLayer: M=512, N=128 atoms, F=512, HID=128. fp32 in, fp32 out.
// out[m,f] = sum_n sigmoid(relu(h[m,n,:]@W1+b1)@W2+b2) * h[m,n,f]
//
// R6 lesson: ~68us invariant across designs = exposed staging latency
// (compiler interleaves vmcnt waits) + too-low block residency (80 KiB LDS).
// R7: ABLK=32 / grid 2048 / 49.5 KiB LDS -> 3 blocks/CU; A staged with all
// loads issued before packing; B tiles DMA'd via global_load_lds (16B) into
// double-buffered LDS with linear layout [tile][quad][hid][8] (conflict-free
// fragment reads); h HBM-read exactly once, phase 2 from swizzled LDS.

typedef unsigned short u16;
typedef unsigned int u32;
typedef __bf16 bf16x8 __attribute__((ext_vector_type(8)));
typedef float f32x4 __attribute__((ext_vector_type(4)));
typedef float f32x2 __attribute__((ext_vector_type(2)));
typedef u32 u32x4 __attribute__((ext_vector_type(4)));

#define M_MOL 512
#define F_DIM 512
#define HID_DIM 128
#define ABLK 32            // atoms per block
#define NBLK (M_MOL * 4)   // 2048 blocks, 4 per molecule

static __device__ __forceinline__ u16 f2bf(float x) {
  u32 u = __float_as_uint(x);
  u32 r = (u + 0x7fffu + ((u >> 16) & 1u)) >> 16;  // RNE
  return (u16)r;
}
// repack two fp32x4 -> bf16x8 by truncation (|rel err| <= 2^-8)
static __device__ __forceinline__ bf16x8 pack8(u32x4 a, u32x4 b) {
  u32x4 r;
  r[0] = (a[0] >> 16) | (a[1] & 0xffff0000u);
  r[1] = (a[2] >> 16) | (a[3] & 0xffff0000u);
  r[2] = (b[0] >> 16) | (b[1] & 0xffff0000u);
  r[3] = (b[2] >> 16) | (b[3] & 0xffff0000u);
  return __builtin_bit_cast(bf16x8, r);
}

// ---- Kernel 1: W1 fp32 [F=512][HID=128] -> W1Tt bf16 [16][4][128][8] ----
// tile ks = [quad][hid][8 k-elems], 8 KiB contiguous, linear-DMA-able.
__global__ __launch_bounds__(256) void transpose_w1(const float* __restrict__ W1,
                                                    u16* __restrict__ W1Tt) {
  __shared__ float tile[64][65];
  const int k0 = blockIdx.x * 64;
  const int n0 = blockIdx.y * 64;
  const int t = threadIdx.x;
  #pragma unroll
  for (int i = 0; i < 16; ++i) {
    const int lin = i * 256 + t;
    const int lr = lin >> 6, lc = lin & 63;
    tile[lc][lr] = W1[(size_t)(k0 + lr) * HID_DIM + (n0 + lc)];
  }
  __syncthreads();
  #pragma unroll
  for (int i = 0; i < 16; ++i) {
    const int lin = i * 256 + t;
    const int wr = lin >> 6, wc = lin & 63;   // wr: hid idx, wc: k idx
    const int k = k0 + wc;
    const int hid = n0 + wr;
    W1Tt[(size_t)(((k >> 5) * 4 + ((k >> 3) & 3)) * HID_DIM + hid) * 8 + (k & 7)] =
        f2bf(tile[wr][wc]);
  }
}

// ---- Kernel 2: 32-atom partial pooling; 256 threads (4 waves) ----
__global__ __launch_bounds__(256, 3) void pool_partial(
    const float* __restrict__ h, const u16* __restrict__ W1Tt,
    const float* __restrict__ b1, const float* __restrict__ W2,
    const float* __restrict__ b2, float* __restrict__ part) {
  // As: h bf16, 32 rows x 512; 16-B chunk c of row r at (c&~7)|((c^r)&7).
  __shared__ u16 As[ABLK * F_DIM];     // 32 KiB
  __shared__ u16 bt[2][4096];          // 16 KiB, double-buffered B tiles
  __shared__ float wred[2][ABLK];      // 256 B
  __shared__ float w_s[ABLK];          // 128 B

  const int blk = blockIdx.x;
  const int tid = threadIdx.x;
  const int wv = tid >> 6;       // wave 0..3
  const int lane = tid & 63;
  const int quad = lane >> 4;
  const int cl = lane & 15;
  const int strip = wv >> 1;     // 0..1: atom strip (16 atoms)
  const int hh = wv & 1;         // 0..1: hid half (4 tiles)

  // --- B tile DMA: wave wv moves bytes [wv*2048, +2048) of the 8-KiB tile ---
  const u16* gB = W1Tt + wv * 1024 + lane * 8;   // +lane*16 B
  #define DMA_TILE(ks, buf)                                                        \
    do {                                                                           \
      const u16* _g = gB + (size_t)(ks) * 4096;                                    \
      u16* _l = &bt[buf][wv * 1024];                                               \
      __builtin_amdgcn_global_load_lds(                                            \
          (const __attribute__((address_space(1))) u32*)(const void*)_g,           \
          (__attribute__((address_space(3))) u32*)(void*)_l, 16, 0, 0);            \
      __builtin_amdgcn_global_load_lds(                                            \
          (const __attribute__((address_space(1))) u32*)(const void*)(_g + 512),   \
          (__attribute__((address_space(3))) u32*)(void*)(_l + 512), 16, 0, 0);    \
    } while (0)

  DMA_TILE(0, 0);   // tile 0 in flight during A staging

  // --- Stage A: 64 KiB fp32 -> 32 KiB bf16 LDS; all loads issued first ---
  {
    const u32x4* hg = (const u32x4*)(h + (size_t)blk * ABLK * F_DIM);
    u32x4 L[8], H[8];
    #pragma unroll
    for (int i = 0; i < 8; ++i) {
      const int u = i * 256 + tid;          // 32-B unit (0..2047)
      L[i] = hg[2 * u];
      H[i] = hg[2 * u + 1];
    }
    #pragma unroll
    for (int i = 0; i < 8; ++i) {
      const int u = i * 256 + tid;
      const int row = u >> 6, c = u & 63;
      const int phys = (c & ~7) | ((c ^ row) & 7);
      *(bf16x8*)(As + row * F_DIM + phys * 8) = pack8(L[i], H[i]);
    }
  }
  __syncthreads();   // As ready; DMA tile0 drained (vmcnt(0) before barrier)

  // --- Phase 1: T[atom][hid] = h @ W1; wave = (strip, hid-half) ---
  f32x4 acc[4];
  #pragma unroll
  for (int t = 0; t < 4; ++t) acc[t] = (f32x4){0.f, 0.f, 0.f, 0.f};

  const int ar = strip * 16 + cl;
  const u16* aBase = As + ar * F_DIM;

  for (int ks = 0; ks < 16; ++ks) {
    if (ks < 15) DMA_TILE(ks + 1, (ks + 1) & 1);
    const int c = ks * 4 + quad;
    const int aphys = (c & ~7) | ((c ^ ar) & 7);
    bf16x8 afr = *(const bf16x8*)(aBase + aphys * 8);
    const u16* bb = bt[ks & 1] + quad * (HID_DIM * 8);
    #pragma unroll
    for (int t = 0; t < 4; ++t) {
      bf16x8 bfr = *(const bf16x8*)(bb + ((hh * 4 + t) * 16 + cl) * 8);
      acc[t] = __builtin_amdgcn_mfma_f32_16x16x32_bf16(afr, bfr, acc[t], 0, 0, 0);
    }
    if (ks < 15) __syncthreads();  // publish next tile; prev fully consumed
  }

  // --- Epilogue: w[atom] = sigmoid(relu(T+b1)@W2 + b2) ---
  float psum[4] = {0.f, 0.f, 0.f, 0.f};
  #pragma unroll
  for (int t = 0; t < 4; ++t) {
    const int hid = (hh * 4 + t) * 16 + cl;
    const float b1v = b1[hid];
    const float w2v = W2[hid];
    #pragma unroll
    for (int r = 0; r < 4; ++r) {
      float tv = fmaxf(acc[t][r] + b1v, 0.f);
      psum[r] = fmaf(tv, w2v, psum[r]);
    }
  }
  #pragma unroll
  for (int off = 1; off < 16; off <<= 1)
    #pragma unroll
    for (int r = 0; r < 4; ++r)
      psum[r] += __shfl_xor(psum[r], off, 64);
  if (cl == 0) {
    #pragma unroll
    for (int r = 0; r < 4; ++r)
      wred[hh][strip * 16 + quad * 4 + r] = psum[r];
  }
  __syncthreads();
  if (tid < ABLK)
    w_s[tid] = 1.f / (1.f + __expf(-(wred[0][tid] + wred[1][tid] + b2[0])));
  __syncthreads();

  // --- Phase 2: partial[f] = sum over 32 atoms of w * h (from LDS) ---
  float facc[8] = {0.f, 0.f, 0.f, 0.f, 0.f, 0.f, 0.f, 0.f};
  #pragma unroll
  for (int i = 0; i < 8; ++i) {
    const int row = wv * 8 + i;
    const float wn = w_s[row];
    const int phys = (lane & ~7) | ((lane ^ row) & 7);
    bf16x8 hv = *(const bf16x8*)(As + row * F_DIM + phys * 8);
    u32x4 uv = __builtin_bit_cast(u32x4, hv);
    #pragma unroll
    for (int j = 0; j < 4; ++j) {
      facc[2 * j]     = fmaf(wn, __uint_as_float(uv[j] << 16), facc[2 * j]);
      facc[2 * j + 1] = fmaf(wn, __uint_as_float(uv[j] & 0xffff0000u), facc[2 * j + 1]);
    }
  }
  float (*red)[F_DIM] = (float (*)[F_DIM])bt;   // reuse 16 KiB (phase 1 done)
  #pragma unroll
  for (int j = 0; j < 8; ++j) red[wv][lane * 8 + j] = facc[j];
  __syncthreads();

  {
    const int f = tid * 2;
    f32x2 o;
    o[0] = red[0][f] + red[1][f] + red[2][f] + red[3][f];
    o[1] = red[0][f + 1] + red[1][f + 1] + red[2][f + 1] + red[3][f + 1];
    *(f32x2*)(part + (size_t)blk * F_DIM + f) = o;
  }
}

// ---- Kernel 3: out[m] = sum of 4 partials ----
__global__ __launch_bounds__(256) void reduce_out(const float* __restrict__ part,
                                                  float* __restrict__ out) {
  const int m = blockIdx.x;
  const int f = threadIdx.x * 2;
  f32x2 o = (f32x2){0.f, 0.f};
  #pragma unroll
  for (int p = 0; p < 4; ++p) {
    f32x2 a = *(const f32x2*)(part + (size_t)(4 * m + p) * F_DIM + f);
    o[0] += a[0];
    o[1] += a[1];
  }
  *(f32x2*)(out + (size_t)m * F_DIM + f) = o;
}

extern "C" void kernel_launch(void* const* d_in, const int* in_sizes, int n_in,
                              void* d_out, int out_size, void* d_ws, size_t ws_size,
                              hipStream_t stream) {
  const float* h  = (const float*)d_in[0];   // [512,128,512] fp32
  const float* W1 = (const float*)d_in[1];   // [512,128] fp32
  const float* b1 = (const float*)d_in[2];   // [128] fp32
  const float* W2 = (const float*)d_in[3];   // [128,1] fp32
  const float* b2 = (const float*)d_in[4];   // [1] fp32
  float* out = (float*)d_out;                // [512,512] fp32

  u16* W1Tt = (u16*)d_ws;                                               // 128 KiB
  float* part = (float*)((char*)d_ws + (size_t)HID_DIM * F_DIM * sizeof(u16));  // 4 MiB

  transpose_w1<<<dim3(8, 2), 256, 0, stream>>>(W1, W1Tt);
  pool_partial<<<NBLK, 256, 0, stream>>>(h, W1Tt, b1, W2, b2, part);
  reduce_out<<<M_MOL, 256, 0, stream>>>(part, out);
}